// Round 5
// baseline (70.233 us; speedup 1.0000x reference)
//
#include <hip/hip_runtime.h>

#define L_LEN 8192
#define H_DIM 512
#define P_DIM 256
#define N2P   512
#define CHUNKS 512
#define CLEN  (L_LEN / CHUNKS)

typedef short bf16x8 __attribute__((ext_vector_type(8)));
typedef float f32x4  __attribute__((ext_vector_type(4)));

// ---- workspace layout (FLOAT offsets) ----
#define OFF_BMT   0                          // bf16 [512][512] -> 131072 floats
#define OFF_W2T   (OFF_BMT + 131072)         // bf16 [512][512] -> 131072 floats
#define OFF_LBRE  (OFF_W2T + 131072)
#define OFF_LBIM  (OFF_LBRE + 256)
#define OFF_BU    (OFF_LBIM + 256)           // bf16 [L][512] -> 2097152 floats
#define OFF_XC    (OFF_BU + 2097152)         // bf16 [L][512] -> 2097152 floats
#define OFF_AGAR  (OFF_XC + 2097152)
#define OFF_AGAI  (OFF_AGAR + CHUNKS * P_DIM)
#define OFF_AGBR  (OFF_AGAI + CHUNKS * P_DIM)
#define OFF_AGBI  (OFF_AGBR + CHUNKS * P_DIM)
#define OFF_AGC   (OFF_AGBI + CHUNKS * P_DIM)
#define OFF_CARR  (OFF_AGC  + CHUNKS)
#define OFF_CARI  (OFF_CARR + CHUNKS * P_DIM)

__device__ __forceinline__ unsigned short bfr(float x) {
    unsigned u = __float_as_uint(x);
    u = (u + 0x7fffu + ((u >> 16) & 1u)) >> 16;
    return (unsigned short)u;
}
__device__ __forceinline__ unsigned pk(float a, float b) {
    return (unsigned)bfr(a) | ((unsigned)bfr(b) << 16);
}
__device__ __forceinline__ float b2f(unsigned short v) {
    return __uint_as_float(((unsigned)v) << 16);
}
__device__ __forceinline__ void gl2lds16(const void* g, void* l) {
    __builtin_amdgcn_global_load_lds(
        (const __attribute__((address_space(1))) void*)g,
        (__attribute__((address_space(3))) void*)l, 16, 0, 0);
}

// ---------------------------------------------------------------------------
// K0: precompute Lambda_bar, BmT (bf16 [2P][H]), W2T (bf16 [H][2P] interleaved)
// ---------------------------------------------------------------------------
__global__ __launch_bounds__(256) void s5_k0(
    const float* __restrict__ Lre, const float* __restrict__ Lim,
    const float* __restrict__ logstep,
    const float* __restrict__ B,   // (P,H,2)
    const float* __restrict__ C,   // (H,P,2)
    short* __restrict__ BmT, unsigned* __restrict__ W2Tu,
    float* __restrict__ Lbre, float* __restrict__ Lbim)
{
    int idx = blockIdx.x * 256 + threadIdx.x;   // 0 .. 131071

    int p = idx >> 9, h = idx & 511;
    float lre = Lre[p], lim = Lim[p];
    float s = expf(logstep[p]);
    float er = expf(lre * s);
    float lbr = er * cosf(lim * s);
    float lbi = er * sinf(lim * s);
    if (h == 0) { Lbre[p] = lbr; Lbim[p] = lbi; }
    float nr = lbr - 1.0f, ni = lbi;
    float inv = 1.0f / (lre * lre + lim * lim);
    float fr = (nr * lre + ni * lim) * inv;
    float fi = (ni * lre - nr * lim) * inv;
    float b0 = B[2 * idx + 0];
    float b1 = B[2 * idx + 1];
    BmT[(size_t)p * 512 + h]         = (short)bfr(fr * b0 - fi * b1);
    BmT[(size_t)(256 + p) * 512 + h] = (short)bfr(fr * b1 + fi * b0);

    int hh = idx >> 8, pp = idx & 255;
    float cre = C[2 * idx + 0];
    float cim = C[2 * idx + 1];
    W2Tu[(size_t)hh * 256 + pp] = pk(2.0f * cre, -2.0f * cim);
}

// ---------------------------------------------------------------------------
// bf16 MFMA GEMM: Out[M=8192][512] = A[M][512] @ WT[512][512]^T
// BM=128, BN=64, BK=64. 256 thr (4 waves, 2x2; wave tile 64x32).
// Double-buffered linear LDS; global_load_lds for bf16 operands;
// fp32 A reg-staged + converted (T14 split: load early, ds_write after MFMA).
// AFP32: A fp32 -> out bf16 (GEMM1).  !AFP32: A bf16 -> out fp32 + EPI (GEMM2).
// ---------------------------------------------------------------------------
template<bool AFP32, bool EPI>
__global__ __launch_bounds__(256) void s5_gemm(
    const void* __restrict__ Ap, const short* __restrict__ WT,
    const float* __restrict__ u, const float* __restrict__ Dv,
    void* __restrict__ Outp)
{
    __shared__ __align__(16) short sA[2][128][64];
    __shared__ __align__(16) short sB[2][64][64];

    const int tid = threadIdx.x;
    const int rowBase = blockIdx.y * 128;
    const int colBase = blockIdx.x * 64;

    const int w = tid >> 6, l = tid & 63;
    const int wr = (w >> 1) * 64, wc = (w & 1) * 32;
    const int fr = l & 15, fq = l >> 4;

    float4 fa[8];
    f32x4 acc[4][2] = {};

    auto STAGE_B = [&](int bf, int t) {
        const int kk = t * 64;
        #pragma unroll
        for (int i = 0; i < 2; ++i) {
            int e = i * 256 + tid;
            int row = e >> 3, c8 = (e & 7) << 3;
            gl2lds16(WT + (size_t)(colBase + row) * 512 + kk + c8, &sB[bf][row][c8]);
        }
    };
    auto STAGE_A16 = [&](int bf, int t) {
        const int kk = t * 64;
        const short* A = (const short*)Ap;
        #pragma unroll
        for (int i = 0; i < 4; ++i) {
            int e = i * 256 + tid;
            int row = e >> 3, c8 = (e & 7) << 3;
            gl2lds16(A + (size_t)(rowBase + row) * 512 + kk + c8, &sA[bf][row][c8]);
        }
    };
    auto LOADA_REG = [&](int t) {
        const int kk = t * 64;
        const float* A = (const float*)Ap;
        #pragma unroll
        for (int i = 0; i < 4; ++i) {
            int e = i * 256 + tid;
            int row = e >> 3, c8 = (e & 7) << 3;
            const float4* s = (const float4*)(A + (size_t)(rowBase + row) * 512 + kk + c8);
            fa[2 * i] = s[0]; fa[2 * i + 1] = s[1];
        }
    };
    auto CONVA_WRITE = [&](int bf) {
        #pragma unroll
        for (int i = 0; i < 4; ++i) {
            int e = i * 256 + tid;
            int row = e >> 3, c8 = (e & 7) << 3;
            float4 f0 = fa[2 * i], f1 = fa[2 * i + 1];
            int4 wv = make_int4((int)pk(f0.x, f0.y), (int)pk(f0.z, f0.w),
                                (int)pk(f1.x, f1.y), (int)pk(f1.z, f1.w));
            *(int4*)&sA[bf][row][c8] = wv;
        }
    };
    auto COMPUTE = [&](int bf) {
        #pragma unroll
        for (int kc = 0; kc < 2; ++kc) {
            bf16x8 av[4], bv[2];
            #pragma unroll
            for (int i = 0; i < 4; ++i)
                av[i] = *(const bf16x8*)&sA[bf][wr + 16 * i + fr][kc * 32 + 8 * fq];
            #pragma unroll
            for (int j = 0; j < 2; ++j)
                bv[j] = *(const bf16x8*)&sB[bf][wc + 16 * j + fr][kc * 32 + 8 * fq];
            #pragma unroll
            for (int i = 0; i < 4; ++i)
                #pragma unroll
                for (int j = 0; j < 2; ++j)
                    acc[i][j] = __builtin_amdgcn_mfma_f32_16x16x32_bf16(av[i], bv[j], acc[i][j], 0, 0, 0);
        }
    };

    // prologue
    if (AFP32) { LOADA_REG(0); CONVA_WRITE(0); } else { STAGE_A16(0, 0); }
    STAGE_B(0, 0);
    __syncthreads();

    for (int t = 0; t < 8; ++t) {
        const int cur = t & 1, nxt = cur ^ 1;
        if (t < 7) {
            STAGE_B(nxt, t + 1);
            if (AFP32) LOADA_REG(t + 1); else STAGE_A16(nxt, t + 1);
        }
        COMPUTE(cur);
        if (AFP32 && t < 7) CONVA_WRITE(nxt);
        __syncthreads();
    }

    if (AFP32) {
        unsigned short* Out = (unsigned short*)Outp;
        #pragma unroll
        for (int i = 0; i < 4; ++i)
            #pragma unroll
            for (int j = 0; j < 2; ++j)
                #pragma unroll
                for (int q = 0; q < 4; ++q) {
                    int r = rowBase + wr + 16 * i + fq * 4 + q;
                    int c = colBase + wc + 16 * j + fr;
                    Out[(size_t)r * 512 + c] = bfr(acc[i][j][q]);
                }
    } else {
        float* Out = (float*)Outp;
        float dj[2];
        #pragma unroll
        for (int j = 0; j < 2; ++j) dj[j] = EPI ? Dv[colBase + wc + 16 * j + fr] : 0.f;
        #pragma unroll
        for (int i = 0; i < 4; ++i)
            #pragma unroll
            for (int j = 0; j < 2; ++j)
                #pragma unroll
                for (int q = 0; q < 4; ++q) {
                    int r = rowBase + wr + 16 * i + fq * 4 + q;
                    int c = colBase + wc + 16 * j + fr;
                    float v = acc[i][j][q];
                    if (EPI) v += u[(size_t)r * 512 + c] * dj[j];
                    Out[(size_t)r * 512 + c] = v;
                }
    }
}

// ---------------------------------------------------------------------------
// K2: per-chunk aggregates (Bu is bf16)
// ---------------------------------------------------------------------------
__global__ __launch_bounds__(P_DIM) void s5_k2(
    const unsigned short* __restrict__ Bu, const int* __restrict__ resets,
    const float* __restrict__ Lbre, const float* __restrict__ Lbim,
    float* __restrict__ aAr, float* __restrict__ aAi,
    float* __restrict__ aBr, float* __restrict__ aBi, float* __restrict__ aC)
{
    const int p = threadIdx.x, ci = blockIdx.x;
    const float lbr = Lbre[p], lbi = Lbim[p];
    float Ar = 1.f, Ai = 0.f, br = 0.f, bi = 0.f;
    int c = 0;
    const int t0 = ci * CLEN;
    for (int t = t0; t < t0 + CLEN; ++t) {
        int rs = resets[t];
        float bur = b2f(Bu[(size_t)t * 512 + p]);
        float bui = b2f(Bu[(size_t)t * 512 + 256 + p]);
        if (rs) { Ar = lbr; Ai = lbi; br = bur; bi = bui; c = 1; }
        else {
            float nAr = lbr * Ar - lbi * Ai; Ai = lbr * Ai + lbi * Ar; Ar = nAr;
            float nbr = lbr * br - lbi * bi + bur; bi = lbr * bi + lbi * br + bui; br = nbr;
        }
    }
    aAr[ci * P_DIM + p] = Ar; aAi[ci * P_DIM + p] = Ai;
    aBr[ci * P_DIM + p] = br; aBi[ci * P_DIM + p] = bi;
    if (p == 0) aC[ci] = (float)c;
}

// ---------------------------------------------------------------------------
// K3p: parallel Hillis-Steele scan over chunk aggregates -> carry per chunk
// ---------------------------------------------------------------------------
__global__ __launch_bounds__(CHUNKS) void s5_k3p(
    const float* __restrict__ hidden,
    const float* __restrict__ aAr, const float* __restrict__ aAi,
    const float* __restrict__ aBr, const float* __restrict__ aBi,
    const float* __restrict__ aC,
    float* __restrict__ carR, float* __restrict__ carI)
{
    __shared__ float sAr[CHUNKS], sAi[CHUNKS], sBr[CHUNKS], sBi[CHUNKS], sC[CHUNKS];
    const int p = blockIdx.x, t = threadIdx.x;

    float Ar = aAr[t * P_DIM + p], Ai = aAi[t * P_DIM + p];
    float br = aBr[t * P_DIM + p], bi = aBi[t * P_DIM + p];
    float c  = aC[t];
    sAr[t] = Ar; sAi[t] = Ai; sBr[t] = br; sBi[t] = bi; sC[t] = c;
    __syncthreads();

    for (int s = 1; s < CHUNKS; s <<= 1) {
        float pAr = 0.f, pAi = 0.f, pBr = 0.f, pBi = 0.f, pC = 0.f;
        const bool has = (t >= s);
        if (has) { pAr = sAr[t-s]; pAi = sAi[t-s]; pBr = sBr[t-s]; pBi = sBi[t-s]; pC = sC[t-s]; }
        __syncthreads();
        if (has) {
            if (c <= 0.5f) {
                float nAr = Ar * pAr - Ai * pAi;
                float nAi = Ar * pAi + Ai * pAr;
                float nbr = Ar * pBr - Ai * pBi + br;
                float nbi = Ar * pBi + Ai * pBr + bi;
                Ar = nAr; Ai = nAi; br = nbr; bi = nbi; c = pC;
            }
            sAr[t] = Ar; sAi[t] = Ai; sBr[t] = br; sBi[t] = bi; sC[t] = c;
        }
        __syncthreads();
    }

    const float h = hidden[p];
    float sr, si;
    if (t == 0) { sr = h; si = 0.f; }
    else {
        float gAr = sAr[t-1], gAi = sAi[t-1], gBr = sBr[t-1], gBi = sBi[t-1], gC = sC[t-1];
        if (gC > 0.5f) { sr = gBr; si = gBi; }
        else           { sr = gAr * h + gBr; si = gAi * h + gBi; }
    }
    carR[t * P_DIM + p] = sr;
    carI[t * P_DIM + p] = si;
}

// ---------------------------------------------------------------------------
// K4: re-scan with carry (Bu bf16), write xs as packed bf16 (re,im)
// ---------------------------------------------------------------------------
__global__ __launch_bounds__(P_DIM) void s5_k4(
    const unsigned short* __restrict__ Bu, const int* __restrict__ resets,
    const float* __restrict__ Lbre, const float* __restrict__ Lbim,
    const float* __restrict__ carR, const float* __restrict__ carI,
    unsigned* __restrict__ xcu)
{
    const int p = threadIdx.x, ci = blockIdx.x;
    const float lbr = Lbre[p], lbi = Lbim[p];
    float sr = carR[ci * P_DIM + p];
    float si = carI[ci * P_DIM + p];
    const int t0 = ci * CLEN;
    for (int t = t0; t < t0 + CLEN; ++t) {
        int rs = resets[t];
        float bur = b2f(Bu[(size_t)t * 512 + p]);
        float bui = b2f(Bu[(size_t)t * 512 + 256 + p]);
        if (rs) { sr = bur; si = bui; }
        else {
            float nr = lbr * sr - lbi * si + bur;
            si = lbr * si + lbi * sr + bui;
            sr = nr;
        }
        xcu[(size_t)t * 256 + p] = pk(sr, si);
    }
}

// ---------------------------------------------------------------------------
extern "C" void kernel_launch(void* const* d_in, const int* in_sizes, int n_in,
                              void* d_out, int out_size, void* d_ws, size_t ws_size,
                              hipStream_t stream)
{
    const float* hidden  = (const float*)d_in[0];
    const float* u       = (const float*)d_in[1];
    const float* Lre     = (const float*)d_in[2];
    const float* Lim     = (const float*)d_in[3];
    const float* B       = (const float*)d_in[4];
    const float* C       = (const float*)d_in[5];
    const float* D       = (const float*)d_in[6];
    const float* logstep = (const float*)d_in[7];
    const int*   resets  = (const int*)d_in[8];
    float* out = (float*)d_out;
    float* ws  = (float*)d_ws;

    short*          BmT  = (short*)(ws + OFF_BMT);
    short*          W2T  = (short*)(ws + OFF_W2T);
    unsigned*       W2Tu = (unsigned*)(ws + OFF_W2T);
    float*          Lbre = ws + OFF_LBRE;
    float*          Lbim = ws + OFF_LBIM;
    unsigned short* Bu   = (unsigned short*)(ws + OFF_BU);
    short*          xc   = (short*)(ws + OFF_XC);
    unsigned*       xcu  = (unsigned*)(ws + OFF_XC);

    s5_k0<<<512, 256, 0, stream>>>(Lre, Lim, logstep, B, C, BmT, W2Tu, Lbre, Lbim);

    // GEMM1: Bu(bf16) = u(fp32) @ BmT^T
    s5_gemm<true, false><<<dim3(N2P / 64, L_LEN / 128), 256, 0, stream>>>(
        (const void*)u, BmT, nullptr, nullptr, (void*)Bu);

    s5_k2<<<CHUNKS, P_DIM, 0, stream>>>(Bu, resets, Lbre, Lbim,
        ws + OFF_AGAR, ws + OFF_AGAI, ws + OFF_AGBR, ws + OFF_AGBI, ws + OFF_AGC);

    s5_k3p<<<P_DIM, CHUNKS, 0, stream>>>(hidden,
        ws + OFF_AGAR, ws + OFF_AGAI, ws + OFF_AGBR, ws + OFF_AGBI, ws + OFF_AGC,
        ws + OFF_CARR, ws + OFF_CARI);

    s5_k4<<<CHUNKS, P_DIM, 0, stream>>>(Bu, resets, Lbre, Lbim,
        ws + OFF_CARR, ws + OFF_CARI, xcu);

    // GEMM2: out(fp32) = xc(bf16) @ W2T^T + u*D
    s5_gemm<false, true><<<dim3(H_DIM / 64, L_LEN / 128), 256, 0, stream>>>(
        (const void*)xc, W2T, u, D, (void*)out);
}

// Round 6
// 62.265 us; speedup vs baseline: 1.1280x; 1.1280x over previous
//
#include <hip/hip_runtime.h>

#define L_LEN 8192
#define H_DIM 512
#define P_DIM 256
#define N2P   512
#define CHUNKS 512
#define CLEN  (L_LEN / CHUNKS)

typedef short bf16x8 __attribute__((ext_vector_type(8)));
typedef float f32x4  __attribute__((ext_vector_type(4)));

// ---- workspace layout (FLOAT offsets) ----
#define OFF_BMT   0                          // bf16 [512][512] -> 131072 floats
#define OFF_W2T   (OFF_BMT + 131072)         // bf16 [512][512] -> 131072 floats
#define OFF_LBRE  (OFF_W2T + 131072)
#define OFF_LBIM  (OFF_LBRE + 256)
#define OFF_BU    (OFF_LBIM + 256)           // bf16 [L][512] -> 2097152 floats
#define OFF_XC    (OFF_BU + 2097152)         // bf16 [L][512] -> 2097152 floats
#define OFF_AGAR  (OFF_XC + 2097152)
#define OFF_AGAI  (OFF_AGAR + CHUNKS * P_DIM)
#define OFF_AGBR  (OFF_AGAI + CHUNKS * P_DIM)
#define OFF_AGBI  (OFF_AGBR + CHUNKS * P_DIM)
#define OFF_AGC   (OFF_AGBI + CHUNKS * P_DIM)
#define OFF_CARR  (OFF_AGC  + CHUNKS)
#define OFF_CARI  (OFF_CARR + CHUNKS * P_DIM)

__device__ __forceinline__ unsigned short bfr(float x) {
    unsigned u = __float_as_uint(x);
    u = (u + 0x7fffu + ((u >> 16) & 1u)) >> 16;
    return (unsigned short)u;
}
__device__ __forceinline__ unsigned pk(float a, float b) {
    return (unsigned)bfr(a) | ((unsigned)bfr(b) << 16);
}
__device__ __forceinline__ float b2f(unsigned short v) {
    return __uint_as_float(((unsigned)v) << 16);
}
__device__ __forceinline__ void gl2lds16(const void* g, void* l) {
    __builtin_amdgcn_global_load_lds(
        (const __attribute__((address_space(1))) void*)g,
        (__attribute__((address_space(3))) void*)l, 16, 0, 0);
}

// ---------------------------------------------------------------------------
// K0: precompute Lambda_bar, BmT (bf16 [2P][H]), W2T (bf16 [H][2P] interleaved)
// ---------------------------------------------------------------------------
__global__ __launch_bounds__(256) void s5_k0(
    const float* __restrict__ Lre, const float* __restrict__ Lim,
    const float* __restrict__ logstep,
    const float* __restrict__ B,   // (P,H,2)
    const float* __restrict__ C,   // (H,P,2)
    short* __restrict__ BmT, unsigned* __restrict__ W2Tu,
    float* __restrict__ Lbre, float* __restrict__ Lbim)
{
    int idx = blockIdx.x * 256 + threadIdx.x;   // 0 .. 131071

    int p = idx >> 9, h = idx & 511;
    float lre = Lre[p], lim = Lim[p];
    float s = expf(logstep[p]);
    float er = expf(lre * s);
    float lbr = er * cosf(lim * s);
    float lbi = er * sinf(lim * s);
    if (h == 0) { Lbre[p] = lbr; Lbim[p] = lbi; }
    float nr = lbr - 1.0f, ni = lbi;
    float inv = 1.0f / (lre * lre + lim * lim);
    float fr = (nr * lre + ni * lim) * inv;
    float fi = (ni * lre - nr * lim) * inv;
    float b0 = B[2 * idx + 0];
    float b1 = B[2 * idx + 1];
    BmT[(size_t)p * 512 + h]         = (short)bfr(fr * b0 - fi * b1);
    BmT[(size_t)(256 + p) * 512 + h] = (short)bfr(fr * b1 + fi * b0);

    int hh = idx >> 8, pp = idx & 255;
    float cre = C[2 * idx + 0];
    float cim = C[2 * idx + 1];
    W2Tu[(size_t)hh * 256 + pp] = pk(2.0f * cre, -2.0f * cim);
}

// ---------------------------------------------------------------------------
// bf16 MFMA GEMM: Out[M=8192][512] = A[M][512] @ WT[512][512]^T
// BM=64, BN=256, BK=64. 512 thr = 8 waves (2x4), wave tile 32x64.
// 1-D grid 256: row = bid&127, col = bid>>7 -> column-block pair (bid y, y+128)
// lands on the SAME XCD (same value mod 8) so the 2nd A-pass is an L2 hit.
// AFP32: A fp32 -> out bf16 (GEMM1).  !AFP32: A bf16 -> out fp32 + EPI (GEMM2).
// ---------------------------------------------------------------------------
template<bool AFP32, bool EPI>
__global__ __launch_bounds__(512) void s5_gemm(
    const void* __restrict__ Ap, const short* __restrict__ WT,
    const float* __restrict__ u, const float* __restrict__ Dv,
    void* __restrict__ Outp)
{
    __shared__ __align__(16) short sA[2][64][64];
    __shared__ __align__(16) short sB[2][256][64];

    const int tid = threadIdx.x;
    const int bid = blockIdx.x;
    const int rowBase = (bid & 127) * 64;
    const int colBase = (bid >> 7) * 256;

    const int w = tid >> 6, l = tid & 63;
    const int wr = (w >> 2) * 32, wc = (w & 3) * 64;
    const int fr = l & 15, fq = l >> 4;

    float4 fa[2];
    f32x4 acc[2][4] = {};

    auto STAGE_B = [&](int bf, int t) {
        const int kk = t * 64;
        #pragma unroll
        for (int i = 0; i < 4; ++i) {
            int e = i * 512 + tid;
            int row = e >> 3, c8 = (e & 7) << 3;
            gl2lds16(WT + (size_t)(colBase + row) * 512 + kk + c8, &sB[bf][row][c8]);
        }
    };
    auto STAGE_A16 = [&](int bf, int t) {
        const int kk = t * 64;
        const short* A = (const short*)Ap;
        int row = tid >> 3, c8 = (tid & 7) << 3;
        gl2lds16(A + (size_t)(rowBase + row) * 512 + kk + c8, &sA[bf][row][c8]);
    };
    auto LOADA_REG = [&](int t) {
        const int kk = t * 64;
        const float* A = (const float*)Ap;
        int row = tid >> 3, c8 = (tid & 7) << 3;
        const float4* s = (const float4*)(A + (size_t)(rowBase + row) * 512 + kk + c8);
        fa[0] = s[0]; fa[1] = s[1];
    };
    auto CONVA_WRITE = [&](int bf) {
        int row = tid >> 3, c8 = (tid & 7) << 3;
        int4 wv = make_int4((int)pk(fa[0].x, fa[0].y), (int)pk(fa[0].z, fa[0].w),
                            (int)pk(fa[1].x, fa[1].y), (int)pk(fa[1].z, fa[1].w));
        *(int4*)&sA[bf][row][c8] = wv;
    };
    auto COMPUTE = [&](int bf) {
        #pragma unroll
        for (int kc = 0; kc < 2; ++kc) {
            bf16x8 av[2], bv[4];
            #pragma unroll
            for (int i = 0; i < 2; ++i)
                av[i] = *(const bf16x8*)&sA[bf][wr + 16 * i + fr][kc * 32 + 8 * fq];
            #pragma unroll
            for (int j = 0; j < 4; ++j)
                bv[j] = *(const bf16x8*)&sB[bf][wc + 16 * j + fr][kc * 32 + 8 * fq];
            #pragma unroll
            for (int i = 0; i < 2; ++i)
                #pragma unroll
                for (int j = 0; j < 4; ++j)
                    acc[i][j] = __builtin_amdgcn_mfma_f32_16x16x32_bf16(av[i], bv[j], acc[i][j], 0, 0, 0);
        }
    };

    // prologue
    if (AFP32) { LOADA_REG(0); CONVA_WRITE(0); } else { STAGE_A16(0, 0); }
    STAGE_B(0, 0);
    __syncthreads();

    for (int t = 0; t < 8; ++t) {
        const int cur = t & 1, nxt = cur ^ 1;
        if (t < 7) {
            STAGE_B(nxt, t + 1);
            if (AFP32) LOADA_REG(t + 1); else STAGE_A16(nxt, t + 1);
        }
        COMPUTE(cur);
        if (AFP32 && t < 7) CONVA_WRITE(nxt);
        __syncthreads();
    }

    if (AFP32) {
        unsigned short* Out = (unsigned short*)Outp;
        #pragma unroll
        for (int i = 0; i < 2; ++i)
            #pragma unroll
            for (int j = 0; j < 4; ++j)
                #pragma unroll
                for (int q = 0; q < 4; ++q) {
                    int r = rowBase + wr + 16 * i + fq * 4 + q;
                    int c = colBase + wc + 16 * j + fr;
                    Out[(size_t)r * 512 + c] = bfr(acc[i][j][q]);
                }
    } else {
        float* Out = (float*)Outp;
        float dj[4];
        #pragma unroll
        for (int j = 0; j < 4; ++j) dj[j] = EPI ? Dv[colBase + wc + 16 * j + fr] : 0.f;
        #pragma unroll
        for (int i = 0; i < 2; ++i)
            #pragma unroll
            for (int j = 0; j < 4; ++j)
                #pragma unroll
                for (int q = 0; q < 4; ++q) {
                    int r = rowBase + wr + 16 * i + fq * 4 + q;
                    int c = colBase + wc + 16 * j + fr;
                    float v = acc[i][j][q];
                    if (EPI) v += u[(size_t)r * 512 + c] * dj[j];
                    Out[(size_t)r * 512 + c] = v;
                }
    }
}

// ---------------------------------------------------------------------------
// K2: per-chunk aggregates (Bu is bf16)
// ---------------------------------------------------------------------------
__global__ __launch_bounds__(P_DIM) void s5_k2(
    const unsigned short* __restrict__ Bu, const int* __restrict__ resets,
    const float* __restrict__ Lbre, const float* __restrict__ Lbim,
    float* __restrict__ aAr, float* __restrict__ aAi,
    float* __restrict__ aBr, float* __restrict__ aBi, float* __restrict__ aC)
{
    const int p = threadIdx.x, ci = blockIdx.x;
    const float lbr = Lbre[p], lbi = Lbim[p];
    float Ar = 1.f, Ai = 0.f, br = 0.f, bi = 0.f;
    int c = 0;
    const int t0 = ci * CLEN;
    for (int t = t0; t < t0 + CLEN; ++t) {
        int rs = resets[t];
        float bur = b2f(Bu[(size_t)t * 512 + p]);
        float bui = b2f(Bu[(size_t)t * 512 + 256 + p]);
        if (rs) { Ar = lbr; Ai = lbi; br = bur; bi = bui; c = 1; }
        else {
            float nAr = lbr * Ar - lbi * Ai; Ai = lbr * Ai + lbi * Ar; Ar = nAr;
            float nbr = lbr * br - lbi * bi + bur; bi = lbr * bi + lbi * br + bui; br = nbr;
        }
    }
    aAr[ci * P_DIM + p] = Ar; aAi[ci * P_DIM + p] = Ai;
    aBr[ci * P_DIM + p] = br; aBi[ci * P_DIM + p] = bi;
    if (p == 0) aC[ci] = (float)c;
}

// ---------------------------------------------------------------------------
// K3p: parallel Hillis-Steele scan over chunk aggregates -> carry per chunk
// ---------------------------------------------------------------------------
__global__ __launch_bounds__(CHUNKS) void s5_k3p(
    const float* __restrict__ hidden,
    const float* __restrict__ aAr, const float* __restrict__ aAi,
    const float* __restrict__ aBr, const float* __restrict__ aBi,
    const float* __restrict__ aC,
    float* __restrict__ carR, float* __restrict__ carI)
{
    __shared__ float sAr[CHUNKS], sAi[CHUNKS], sBr[CHUNKS], sBi[CHUNKS], sC[CHUNKS];
    const int p = blockIdx.x, t = threadIdx.x;

    float Ar = aAr[t * P_DIM + p], Ai = aAi[t * P_DIM + p];
    float br = aBr[t * P_DIM + p], bi = aBi[t * P_DIM + p];
    float c  = aC[t];
    sAr[t] = Ar; sAi[t] = Ai; sBr[t] = br; sBi[t] = bi; sC[t] = c;
    __syncthreads();

    for (int s = 1; s < CHUNKS; s <<= 1) {
        float pAr = 0.f, pAi = 0.f, pBr = 0.f, pBi = 0.f, pC = 0.f;
        const bool has = (t >= s);
        if (has) { pAr = sAr[t-s]; pAi = sAi[t-s]; pBr = sBr[t-s]; pBi = sBi[t-s]; pC = sC[t-s]; }
        __syncthreads();
        if (has) {
            if (c <= 0.5f) {
                float nAr = Ar * pAr - Ai * pAi;
                float nAi = Ar * pAi + Ai * pAr;
                float nbr = Ar * pBr - Ai * pBi + br;
                float nbi = Ar * pBi + Ai * pBr + bi;
                Ar = nAr; Ai = nAi; br = nbr; bi = nbi; c = pC;
            }
            sAr[t] = Ar; sAi[t] = Ai; sBr[t] = br; sBi[t] = bi; sC[t] = c;
        }
        __syncthreads();
    }

    const float h = hidden[p];
    float sr, si;
    if (t == 0) { sr = h; si = 0.f; }
    else {
        float gAr = sAr[t-1], gAi = sAi[t-1], gBr = sBr[t-1], gBi = sBi[t-1], gC = sC[t-1];
        if (gC > 0.5f) { sr = gBr; si = gBi; }
        else           { sr = gAr * h + gBr; si = gAi * h + gBi; }
    }
    carR[t * P_DIM + p] = sr;
    carI[t * P_DIM + p] = si;
}

// ---------------------------------------------------------------------------
// K4: re-scan with carry (Bu bf16), write xs as packed bf16 (re,im)
// ---------------------------------------------------------------------------
__global__ __launch_bounds__(P_DIM) void s5_k4(
    const unsigned short* __restrict__ Bu, const int* __restrict__ resets,
    const float* __restrict__ Lbre, const float* __restrict__ Lbim,
    const float* __restrict__ carR, const float* __restrict__ carI,
    unsigned* __restrict__ xcu)
{
    const int p = threadIdx.x, ci = blockIdx.x;
    const float lbr = Lbre[p], lbi = Lbim[p];
    float sr = carR[ci * P_DIM + p];
    float si = carI[ci * P_DIM + p];
    const int t0 = ci * CLEN;
    for (int t = t0; t < t0 + CLEN; ++t) {
        int rs = resets[t];
        float bur = b2f(Bu[(size_t)t * 512 + p]);
        float bui = b2f(Bu[(size_t)t * 512 + 256 + p]);
        if (rs) { sr = bur; si = bui; }
        else {
            float nr = lbr * sr - lbi * si + bur;
            si = lbr * si + lbi * sr + bui;
            sr = nr;
        }
        xcu[(size_t)t * 256 + p] = pk(sr, si);
    }
}

// ---------------------------------------------------------------------------
extern "C" void kernel_launch(void* const* d_in, const int* in_sizes, int n_in,
                              void* d_out, int out_size, void* d_ws, size_t ws_size,
                              hipStream_t stream)
{
    const float* hidden  = (const float*)d_in[0];
    const float* u       = (const float*)d_in[1];
    const float* Lre     = (const float*)d_in[2];
    const float* Lim     = (const float*)d_in[3];
    const float* B       = (const float*)d_in[4];
    const float* C       = (const float*)d_in[5];
    const float* D       = (const float*)d_in[6];
    const float* logstep = (const float*)d_in[7];
    const int*   resets  = (const int*)d_in[8];
    float* out = (float*)d_out;
    float* ws  = (float*)d_ws;

    short*          BmT  = (short*)(ws + OFF_BMT);
    short*          W2T  = (short*)(ws + OFF_W2T);
    unsigned*       W2Tu = (unsigned*)(ws + OFF_W2T);
    float*          Lbre = ws + OFF_LBRE;
    float*          Lbim = ws + OFF_LBIM;
    unsigned short* Bu   = (unsigned short*)(ws + OFF_BU);
    short*          xc   = (short*)(ws + OFF_XC);
    unsigned*       xcu  = (unsigned*)(ws + OFF_XC);

    s5_k0<<<512, 256, 0, stream>>>(Lre, Lim, logstep, B, C, BmT, W2Tu, Lbre, Lbim);

    // GEMM1: Bu(bf16) = u(fp32) @ BmT^T
    s5_gemm<true, false><<<256, 512, 0, stream>>>(
        (const void*)u, BmT, nullptr, nullptr, (void*)Bu);

    s5_k2<<<CHUNKS, P_DIM, 0, stream>>>(Bu, resets, Lbre, Lbim,
        ws + OFF_AGAR, ws + OFF_AGAI, ws + OFF_AGBR, ws + OFF_AGBI, ws + OFF_AGC);

    s5_k3p<<<P_DIM, CHUNKS, 0, stream>>>(hidden,
        ws + OFF_AGAR, ws + OFF_AGAI, ws + OFF_AGBR, ws + OFF_AGBI, ws + OFF_AGC,
        ws + OFF_CARR, ws + OFF_CARI);

    s5_k4<<<CHUNKS, P_DIM, 0, stream>>>(Bu, resets, Lbre, Lbim,
        ws + OFF_CARR, ws + OFF_CARI, xcu);

    // GEMM2: out(fp32) = xc(bf16) @ W2T^T + u*D
    s5_gemm<false, true><<<256, 512, 0, stream>>>(
        (const void*)xc, W2T, u, D, (void*)out);
}

// Round 7
// 60.171 us; speedup vs baseline: 1.1672x; 1.0348x over previous
//
#include <hip/hip_runtime.h>

#define L_LEN 8192
#define H_DIM 512
#define P_DIM 256
#define CHUNKS 512
#define CLEN  (L_LEN / CHUNKS)

typedef short bf16x8 __attribute__((ext_vector_type(8)));
typedef float f32x4  __attribute__((ext_vector_type(4)));

// ---- workspace layout (FLOAT offsets) ----
#define OFF_BMT   0                          // bf16 [512][512] rows: 2p=re,2p+1=im
#define OFF_W2T   (OFF_BMT + 131072)         // bf16 [512][512] k-interleaved C
#define OFF_LBRE  (OFF_W2T + 131072)
#define OFF_LBIM  (OFF_LBRE + 256)
#define OFF_BU    (OFF_LBIM + 256)           // bf16 [L][512] interleaved (2p=re,2p+1=im)
#define OFF_XC    (OFF_BU + 2097152)         // bf16 [L][512] interleaved
#define OFF_AGAR  (OFF_XC + 2097152)
#define OFF_AGAI  (OFF_AGAR + CHUNKS * P_DIM)
#define OFF_AGBR  (OFF_AGAI + CHUNKS * P_DIM)
#define OFF_AGBI  (OFF_AGBR + CHUNKS * P_DIM)
#define OFF_AGC   (OFF_AGBI + CHUNKS * P_DIM)
#define OFF_CARR  (OFF_AGC  + CHUNKS)
#define OFF_CARI  (OFF_CARR + CHUNKS * P_DIM)

__device__ __forceinline__ unsigned short bfr(float x) {
    unsigned u = __float_as_uint(x);
    u = (u + 0x7fffu + ((u >> 16) & 1u)) >> 16;
    return (unsigned short)u;
}
__device__ __forceinline__ unsigned pk(float a, float b) {
    return (unsigned)bfr(a) | ((unsigned)bfr(b) << 16);
}
__device__ __forceinline__ float b2f(unsigned short v) {
    return __uint_as_float(((unsigned)v) << 16);
}
__device__ __forceinline__ void gl2lds16(const void* g, void* l) {
    __builtin_amdgcn_global_load_lds(
        (const __attribute__((address_space(1))) void*)g,
        (__attribute__((address_space(3))) void*)l, 16, 0, 0);
}

// ---------------------------------------------------------------------------
// K0: precompute Lambda_bar, BmT (bf16, rows 2p=re / 2p+1=im), W2T
// ---------------------------------------------------------------------------
__global__ __launch_bounds__(256) void s5_k0(
    const float* __restrict__ Lre, const float* __restrict__ Lim,
    const float* __restrict__ logstep,
    const float* __restrict__ B,   // (P,H,2)
    const float* __restrict__ C,   // (H,P,2)
    short* __restrict__ BmT, unsigned* __restrict__ W2Tu,
    float* __restrict__ Lbre, float* __restrict__ Lbim)
{
    int idx = blockIdx.x * 256 + threadIdx.x;   // 0 .. 131071

    int p = idx >> 9, h = idx & 511;
    float lre = Lre[p], lim = Lim[p];
    float s = expf(logstep[p]);
    float er = expf(lre * s);
    float lbr = er * cosf(lim * s);
    float lbi = er * sinf(lim * s);
    if (h == 0) { Lbre[p] = lbr; Lbim[p] = lbi; }
    float nr = lbr - 1.0f, ni = lbi;
    float inv = 1.0f / (lre * lre + lim * lim);
    float fr = (nr * lre + ni * lim) * inv;
    float fi = (ni * lre - nr * lim) * inv;
    float b0 = B[2 * idx + 0];
    float b1 = B[2 * idx + 1];
    BmT[(size_t)(2 * p) * 512 + h]     = (short)bfr(fr * b0 - fi * b1);
    BmT[(size_t)(2 * p + 1) * 512 + h] = (short)bfr(fr * b1 + fi * b0);

    int hh = idx >> 8, pp = idx & 255;
    float cre = C[2 * idx + 0];
    float cim = C[2 * idx + 1];
    W2Tu[(size_t)hh * 256 + pp] = pk(2.0f * cre, -2.0f * cim);
}

// ---------------------------------------------------------------------------
// bf16 MFMA GEMM: Out[M=8192][512] = A[M][512] @ WT[512][512]^T
// BM=32, BN=256, BK=64. 256 thr = 4 waves (1x4), wave tile 32x64.
// grid 512 = 2 blocks/CU. Decode: row=bid&255, col=bid>>8 -> A-pass pair
// (y, y+256) lands on same XCD (256 % 8 == 0) for L2 reuse.
// AFP32+AGG: A fp32 -> Bu bf16 + fused per-chunk aggregates (GEMM1).
// !AFP32+EPI: A bf16 -> out fp32 + u*D epilogue (GEMM2).
// ---------------------------------------------------------------------------
template<bool AFP32, bool EPI, bool AGG>
__global__ __launch_bounds__(256) void s5_gemm(
    const void* __restrict__ Ap, const short* __restrict__ WT,
    const float* __restrict__ u, const float* __restrict__ Dv,
    void* __restrict__ Outp,
    const int* __restrict__ resets,
    const float* __restrict__ Lbre, const float* __restrict__ Lbim,
    float* __restrict__ aAr, float* __restrict__ aAi,
    float* __restrict__ aBr, float* __restrict__ aBi, float* __restrict__ aC)
{
    __shared__ __align__(16) short sA[2][32][64];
    __shared__ __align__(16) short sB[2][256][64];

    const int tid = threadIdx.x;
    const int bid = blockIdx.x;
    const int rowBase = (bid & 255) * 32;
    const int colBase = (bid >> 8) * 256;

    const int w = tid >> 6, l = tid & 63;
    const int wc = w * 64;
    const int fr = l & 15, fq = l >> 4;

    float4 fa[2];
    f32x4 acc[2][4] = {};

    auto STAGE_B = [&](int bf, int t) {
        const int kk = t * 64;
        #pragma unroll
        for (int i = 0; i < 8; ++i) {
            int e = i * 256 + tid;
            int row = e >> 3, c8 = (e & 7) << 3;
            gl2lds16(WT + (size_t)(colBase + row) * 512 + kk + c8, &sB[bf][row][c8]);
        }
    };
    auto STAGE_A16 = [&](int bf, int t) {
        const int kk = t * 64;
        const short* A = (const short*)Ap;
        int row = tid >> 3, c8 = (tid & 7) << 3;
        gl2lds16(A + (size_t)(rowBase + row) * 512 + kk + c8, &sA[bf][row][c8]);
    };
    auto LOADA_REG = [&](int t) {
        const int kk = t * 64;
        const float* A = (const float*)Ap;
        int row = tid >> 3, c8 = (tid & 7) << 3;
        const float4* s = (const float4*)(A + (size_t)(rowBase + row) * 512 + kk + c8);
        fa[0] = s[0]; fa[1] = s[1];
    };
    auto CONVA_WRITE = [&](int bf) {
        int row = tid >> 3, c8 = (tid & 7) << 3;
        int4 wv = make_int4((int)pk(fa[0].x, fa[0].y), (int)pk(fa[0].z, fa[0].w),
                            (int)pk(fa[1].x, fa[1].y), (int)pk(fa[1].z, fa[1].w));
        *(int4*)&sA[bf][row][c8] = wv;
    };
    auto COMPUTE = [&](int bf) {
        #pragma unroll
        for (int kc = 0; kc < 2; ++kc) {
            bf16x8 av[2], bv[4];
            #pragma unroll
            for (int i = 0; i < 2; ++i)
                av[i] = *(const bf16x8*)&sA[bf][16 * i + fr][kc * 32 + 8 * fq];
            #pragma unroll
            for (int j = 0; j < 4; ++j)
                bv[j] = *(const bf16x8*)&sB[bf][wc + 16 * j + fr][kc * 32 + 8 * fq];
            #pragma unroll
            for (int i = 0; i < 2; ++i)
                #pragma unroll
                for (int j = 0; j < 4; ++j)
                    acc[i][j] = __builtin_amdgcn_mfma_f32_16x16x32_bf16(av[i], bv[j], acc[i][j], 0, 0, 0);
        }
    };

    // prologue
    if (AFP32) { LOADA_REG(0); CONVA_WRITE(0); } else { STAGE_A16(0, 0); }
    STAGE_B(0, 0);
    __syncthreads();

    for (int t = 0; t < 8; ++t) {
        const int cur = t & 1, nxt = cur ^ 1;
        if (t < 7) {
            STAGE_B(nxt, t + 1);
            if (AFP32) LOADA_REG(t + 1); else STAGE_A16(nxt, t + 1);
        }
        COMPUTE(cur);
        if (AFP32 && t < 7) CONVA_WRITE(nxt);
        __syncthreads();
    }

    if (AFP32) {
        // ---- stash output tile (bf16) in LDS (reuse sB[0]: 16KB needed) ----
        short (*sE)[256] = (short(*)[256])(&sB[0][0][0]);
        #pragma unroll
        for (int i = 0; i < 2; ++i)
            #pragma unroll
            for (int j = 0; j < 4; ++j)
                #pragma unroll
                for (int q = 0; q < 4; ++q)
                    sE[16 * i + 4 * fq + q][wc + 16 * j + fr] = (short)bfr(acc[i][j][q]);
        __syncthreads();

        // ---- vectorized Bu global write: 32 shorts per thread ----
        {
            unsigned short* Out = (unsigned short*)Outp;
            int row = tid >> 3, c32 = (tid & 7) * 32;
            unsigned short* gp = Out + (size_t)(rowBase + row) * 512 + colBase + c32;
            int4 v0 = *(int4*)&sE[row][c32];
            int4 v1 = *(int4*)&sE[row][c32 + 8];
            int4 v2 = *(int4*)&sE[row][c32 + 16];
            int4 v3 = *(int4*)&sE[row][c32 + 24];
            *(int4*)&gp[0]  = v0;
            *(int4*)&gp[8]  = v1;
            *(int4*)&gp[16] = v2;
            *(int4*)&gp[24] = v3;
        }

        if (AGG) {
            // ---- fused per-chunk aggregates (2 chunks x 128 channels) ----
            const unsigned* sEu = (const unsigned*)(&sB[0][0][0]);  // [32][128]
            int cil = tid >> 7;               // 0..1 (local chunk)
            int pl  = tid & 127;
            int p   = (colBase >> 1) + pl;
            const float lbr = Lbre[p], lbi = Lbim[p];
            float Ar = 1.f, Ai = 0.f, br = 0.f, bi = 0.f;
            int c = 0;
            const int r0 = cil * 16;
            #pragma unroll 4
            for (int r = r0; r < r0 + 16; ++r) {
                int rs = resets[rowBase + r];
                unsigned v = sEu[r * 128 + pl];
                float bur = b2f((unsigned short)(v & 0xffffu));
                float bui = b2f((unsigned short)(v >> 16));
                if (rs) { Ar = lbr; Ai = lbi; br = bur; bi = bui; c = 1; }
                else {
                    float nAr = lbr * Ar - lbi * Ai; Ai = lbr * Ai + lbi * Ar; Ar = nAr;
                    float nbr = lbr * br - lbi * bi + bur; bi = lbr * bi + lbi * br + bui; br = nbr;
                }
            }
            int ci = (rowBase >> 4) + cil;
            aAr[ci * P_DIM + p] = Ar; aAi[ci * P_DIM + p] = Ai;
            aBr[ci * P_DIM + p] = br; aBi[ci * P_DIM + p] = bi;
            if (pl == 0) aC[ci] = (float)c;
        }
    } else {
        float* Out = (float*)Outp;
        float dj[4];
        #pragma unroll
        for (int j = 0; j < 4; ++j) dj[j] = EPI ? Dv[colBase + wc + 16 * j + fr] : 0.f;
        #pragma unroll
        for (int i = 0; i < 2; ++i)
            #pragma unroll
            for (int j = 0; j < 4; ++j)
                #pragma unroll
                for (int q = 0; q < 4; ++q) {
                    int r = rowBase + 16 * i + fq * 4 + q;
                    int c = colBase + wc + 16 * j + fr;
                    float v = acc[i][j][q];
                    if (EPI) v += u[(size_t)r * 512 + c] * dj[j];
                    Out[(size_t)r * 512 + c] = v;
                }
    }
}

// ---------------------------------------------------------------------------
// K3p: parallel Hillis-Steele scan over chunk aggregates -> carry per chunk
// ---------------------------------------------------------------------------
__global__ __launch_bounds__(CHUNKS) void s5_k3p(
    const float* __restrict__ hidden,
    const float* __restrict__ aAr, const float* __restrict__ aAi,
    const float* __restrict__ aBr, const float* __restrict__ aBi,
    const float* __restrict__ aC,
    float* __restrict__ carR, float* __restrict__ carI)
{
    __shared__ float sAr[CHUNKS], sAi[CHUNKS], sBr[CHUNKS], sBi[CHUNKS], sC[CHUNKS];
    const int p = blockIdx.x, t = threadIdx.x;

    float Ar = aAr[t * P_DIM + p], Ai = aAi[t * P_DIM + p];
    float br = aBr[t * P_DIM + p], bi = aBi[t * P_DIM + p];
    float c  = aC[t];
    sAr[t] = Ar; sAi[t] = Ai; sBr[t] = br; sBi[t] = bi; sC[t] = c;
    __syncthreads();

    for (int s = 1; s < CHUNKS; s <<= 1) {
        float pAr = 0.f, pAi = 0.f, pBr = 0.f, pBi = 0.f, pC = 0.f;
        const bool has = (t >= s);
        if (has) { pAr = sAr[t-s]; pAi = sAi[t-s]; pBr = sBr[t-s]; pBi = sBi[t-s]; pC = sC[t-s]; }
        __syncthreads();
        if (has) {
            if (c <= 0.5f) {
                float nAr = Ar * pAr - Ai * pAi;
                float nAi = Ar * pAi + Ai * pAr;
                float nbr = Ar * pBr - Ai * pBi + br;
                float nbi = Ar * pBi + Ai * pBr + bi;
                Ar = nAr; Ai = nAi; br = nbr; bi = nbi; c = pC;
            }
            sAr[t] = Ar; sAi[t] = Ai; sBr[t] = br; sBi[t] = bi; sC[t] = c;
        }
        __syncthreads();
    }

    const float h = hidden[p];
    float sr, si;
    if (t == 0) { sr = h; si = 0.f; }
    else {
        float gAr = sAr[t-1], gAi = sAi[t-1], gBr = sBr[t-1], gBi = sBi[t-1], gC = sC[t-1];
        if (gC > 0.5f) { sr = gBr; si = gBi; }
        else           { sr = gAr * h + gBr; si = gAi * h + gBi; }
    }
    carR[t * P_DIM + p] = sr;
    carI[t * P_DIM + p] = si;
}

// ---------------------------------------------------------------------------
// K4: re-scan with carry (Bu interleaved bf16 pairs), write xc packed bf16
// ---------------------------------------------------------------------------
__global__ __launch_bounds__(P_DIM) void s5_k4(
    const unsigned* __restrict__ Bu32, const int* __restrict__ resets,
    const float* __restrict__ Lbre, const float* __restrict__ Lbim,
    const float* __restrict__ carR, const float* __restrict__ carI,
    unsigned* __restrict__ xcu)
{
    const int p = threadIdx.x, ci = blockIdx.x;
    const float lbr = Lbre[p], lbi = Lbim[p];
    float sr = carR[ci * P_DIM + p];
    float si = carI[ci * P_DIM + p];
    const int t0 = ci * CLEN;
    for (int t = t0; t < t0 + CLEN; ++t) {
        int rs = resets[t];
        unsigned v = Bu32[(size_t)t * 256 + p];
        float bur = b2f((unsigned short)(v & 0xffffu));
        float bui = b2f((unsigned short)(v >> 16));
        if (rs) { sr = bur; si = bui; }
        else {
            float nr = lbr * sr - lbi * si + bur;
            si = lbr * si + lbi * sr + bui;
            sr = nr;
        }
        xcu[(size_t)t * 256 + p] = pk(sr, si);
    }
}

// ---------------------------------------------------------------------------
extern "C" void kernel_launch(void* const* d_in, const int* in_sizes, int n_in,
                              void* d_out, int out_size, void* d_ws, size_t ws_size,
                              hipStream_t stream)
{
    const float* hidden  = (const float*)d_in[0];
    const float* u       = (const float*)d_in[1];
    const float* Lre     = (const float*)d_in[2];
    const float* Lim     = (const float*)d_in[3];
    const float* B       = (const float*)d_in[4];
    const float* C       = (const float*)d_in[5];
    const float* D       = (const float*)d_in[6];
    const float* logstep = (const float*)d_in[7];
    const int*   resets  = (const int*)d_in[8];
    float* out = (float*)d_out;
    float* ws  = (float*)d_ws;

    short*     BmT  = (short*)(ws + OFF_BMT);
    short*     W2T  = (short*)(ws + OFF_W2T);
    unsigned*  W2Tu = (unsigned*)(ws + OFF_W2T);
    float*     Lbre = ws + OFF_LBRE;
    float*     Lbim = ws + OFF_LBIM;
    unsigned*  Bu32 = (unsigned*)(ws + OFF_BU);
    short*     xc   = (short*)(ws + OFF_XC);
    unsigned*  xcu  = (unsigned*)(ws + OFF_XC);

    s5_k0<<<512, 256, 0, stream>>>(Lre, Lim, logstep, B, C, BmT, W2Tu, Lbre, Lbim);

    // GEMM1: Bu(bf16, interleaved) = u(fp32) @ BmT^T  + fused chunk aggregates
    s5_gemm<true, false, true><<<512, 256, 0, stream>>>(
        (const void*)u, BmT, nullptr, nullptr, (void*)Bu32,
        resets, Lbre, Lbim,
        ws + OFF_AGAR, ws + OFF_AGAI, ws + OFF_AGBR, ws + OFF_AGBI, ws + OFF_AGC);

    s5_k3p<<<P_DIM, CHUNKS, 0, stream>>>(hidden,
        ws + OFF_AGAR, ws + OFF_AGAI, ws + OFF_AGBR, ws + OFF_AGBI, ws + OFF_AGC,
        ws + OFF_CARR, ws + OFF_CARI);

    s5_k4<<<CHUNKS, P_DIM, 0, stream>>>(Bu32, resets, Lbre, Lbim,
        ws + OFF_CARR, ws + OFF_CARI, xcu);

    // GEMM2: out(fp32) = xc(bf16) @ W2T^T + u*D
    s5_gemm<false, true, false><<<512, 256, 0, stream>>>(
        (const void*)xc, W2T, u, D, (void*)out,
        nullptr, nullptr, nullptr, nullptr, nullptr, nullptr, nullptr, nullptr);
}